// Round 17
// baseline (2079.774 us; speedup 1.0000x reference)
//
#include <hip/hip_runtime.h>
#include <hip/hip_bf16.h>
#include <math.h>

// Shapes: B=16, C=256, H=W=96, S=3, OUT_C=64
#define NPOS 9216
#define PERB 2359296ull        // 256*9216 elements (one [C][H*W] plane-set)

typedef unsigned short u16;
typedef __attribute__((ext_vector_type(8))) short short8;  // bf16x8 MFMA frag
typedef __attribute__((ext_vector_type(4))) float f32x4;   // MFMA acc

__device__ inline u16 bfhi(float x) {
    unsigned int b = __float_as_uint(x);
    return (u16)((b + 0x7FFFu + ((b >> 16) & 1u)) >> 16);   // RNE f32->bf16
}
__device__ inline float bf2f(u16 u) { return __uint_as_float(((unsigned int)u) << 16); }

// async global->LDS, 16B per lane (dest = uniform base + lane*16)
typedef const __attribute__((address_space(1))) void* gvp;
typedef __attribute__((address_space(3))) void* lvp;
__device__ __forceinline__ void glds16(const void* g, void* l) {
    __builtin_amdgcn_global_load_lds((gvp)g, (lvp)l, 16, 0, 0);
}

// ---------------------------------------------------------------------------
// Separable positional-encoding table: T[c][p], c=4j+r.
// ---------------------------------------------------------------------------
__global__ __launch_bounds__(256) void tt_kernel(float* __restrict__ T)
{
    int idx = blockIdx.x * 256 + threadIdx.x;   // 0..24575 (256c x 96p)
    int c = idx / 96, p = idx - (idx / 96) * 96;
    int j = c >> 2, r = c & 3;
    float f = expf(-(float)(2 * j) * 0.07195578415f);  // ln(10000)/128
    float x = (float)p * (1.0f / 95.0f) * f;
    T[idx] = (r == 0) ? sinf(x) : (r == 1) ? cosf(x) : 0.0f;
}

// ---------------------------------------------------------------------------
// Weight split: W[s][mat][256][256] f32 -> blocked bf16 hi/lo, XOR-swizzled.
// layout: [s][mat*2+mb][kb][128 rows][4 slots][8] with slot ^= (row>>1)&3
// ---------------------------------------------------------------------------
__global__ __launch_bounds__(256) void wsplit(
    const float* __restrict__ qw, const float* __restrict__ kw,
    const float* __restrict__ vw, u16* __restrict__ whi, u16* __restrict__ wlo)
{
    int bid = blockIdx.x;
    int s = bid / 48, rem = bid % 48;
    int mat = rem / 16, rem2 = rem % 16;
    int mb = rem2 / 8, kb = rem2 % 8;
    const float* W = ((mat == 0) ? qw : (mat == 1) ? kw : vw) + (size_t)s * 65536;
    int t = threadIdx.x;
    int m = t >> 1, kh = (t & 1) * 16;
    const float* src = W + (size_t)(mb * 128 + m) * 256 + kb * 32 + kh;
    int s0 = kh >> 3;                  // 0 or 2
    int sw = (m >> 1) & 3;
    size_t ob = (size_t)s * 196608 + (size_t)((mat * 2 + mb) * 8 + kb) * 4096
              + (size_t)m * 32;
    u16 hv[16], lv[16];
#pragma unroll
    for (int j = 0; j < 16; ++j) {
        float x = src[j];
        u16 h = bfhi(x);
        hv[j] = h;
        lv[j] = bfhi(x - bf2f(h));
    }
    *(uint4*)(whi + ob + ((s0 ^ sw) * 8))       = *(uint4*)hv;
    *(uint4*)(whi + ob + (((s0 + 1) ^ sw) * 8)) = *(uint4*)(hv + 8);
    *(uint4*)(wlo + ob + ((s0 ^ sw) * 8))       = *(uint4*)lv;
    *(uint4*)(wlo + ob + (((s0 + 1) ^ sw) * 8)) = *(uint4*)(lv + 8);
}

// ---------------------------------------------------------------------------
// MFMA QKV GEMM, split-bf16, fat-M (512 thr, 8 waves, M=256 x N=128) with
// DOUBLE-BUFFERED A staging: STAGE_A(t+1) issued before compute(t); counted
// vmcnt(4) at barrier1 (A(t+1) stays in flight - T4); raw s_barrier after
// MFMA.  B converted f32->hi/lo in-LDS each step (single buffer).
// ---------------------------------------------------------------------------
__global__ __launch_bounds__(512, 4) void gemm_qkv_mfma(
    const u16* __restrict__ whi, const u16* __restrict__ wlo,
    const float* __restrict__ srcq, const float* __restrict__ srckv,
    const float* __restrict__ qb, const float* __restrict__ kbias,
    const float* __restrict__ vb, const float* __restrict__ wvis,
    const float* __restrict__ wir, const float* __restrict__ Ttab,
    float* __restrict__ qo, float* __restrict__ ko, float* __restrict__ vo)
{
    __shared__ char LDSBUF[81920];          // A dbuf 2x32KB + B 16KB
    u16* BH = (u16*)(LDSBUF + 65536);       // [128][32]
    u16* BL = BH + 4096;

    int t = threadIdx.x;
    // bijective XCD-chunk swizzle: 216 = 27*8
    int d = blockIdx.x + 3 * blockIdx.y;           // 0..215
    int role = (d & 7) * 27 + (d >> 3);
    int mat = role / 72, bn = role % 72;
    int b = blockIdx.z;

    const float* gB = ((mat == 0) ? srcq : srckv) + (size_t)b * PERB + bn * 128;
    const u16* gA0 = whi + (size_t)(mat * 2) * 32768;
    const u16* gA1 = wlo + (size_t)(mat * 2) * 32768;

    int wv = t >> 6;
    int wm = wv >> 1, wn = wv & 1;
    int rr = t & 15, gq = (t >> 4) & 3;

    int sxor = (gq ^ ((rr >> 1) & 3)) * 8;
    int offA0 = (wm * 64 + rr) * 32 + sxor;        // in [0,8192)
    int offB0 = (wn * 64 + rr) * 32 + sxor;

    // A staging: dest linear = t*8 (AH half) / +4096 (second half); AL +8192
    size_t asrc0 = (size_t)t * 8;
    size_t asrc1 = 32768 + (size_t)t * 8;

    // B-staging mapping: thread covers (n = t&127, k = (t>>7)*8 + j)
    int bn_ = t & 127, bkh = t >> 7;               // bkh 0..3
    int key = (bn_ >> 1) & 3;
    int wrB = bn_ * 32 + ((bkh ^ key) * 8);
    const float* bp = gB + (size_t)(bkh * 8) * NPOS + bn_;

    f32x4 acc[4][4];
#pragma unroll
    for (int i = 0; i < 4; ++i)
#pragma unroll
        for (int j = 0; j < 4; ++j) acc[i][j] = (f32x4){0.f, 0.f, 0.f, 0.f};

    // prologue: stage A(0) into buf0; load B(0) f32 regs
    {
        u16* A = (u16*)LDSBUF;
        glds16(gA0 + asrc0, &A[t * 8]);
        glds16(gA0 + asrc1, &A[t * 8 + 4096]);
        glds16(gA1 + asrc0, &A[t * 8 + 8192]);
        glds16(gA1 + asrc1, &A[t * 8 + 12288]);
    }
    float xv[8];
#pragma unroll
    for (int j = 0; j < 8; ++j) xv[j] = bp[(size_t)j * NPOS];

#pragma unroll
    for (int kq = 0; kq < 8; ++kq) {
        const int cur = kq & 1, nxt = cur ^ 1;
        u16* Acur = (u16*)(LDSBUF + cur * 32768);
        // 1) issue next A tile into the other buffer (stays in flight)
        if (kq < 7) {
            u16* An = (u16*)(LDSBUF + nxt * 32768);
            glds16(gA0 + (kq + 1) * 4096 + asrc0, &An[t * 8]);
            glds16(gA0 + (kq + 1) * 4096 + asrc1, &An[t * 8 + 4096]);
            glds16(gA1 + (kq + 1) * 4096 + asrc0, &An[t * 8 + 8192]);
            glds16(gA1 + (kq + 1) * 4096 + asrc1, &An[t * 8 + 12288]);
        }
        // 2) convert current B regs -> swizzled LDS (hi/lo)
        {
            u16 hv[8], lv[8];
#pragma unroll
            for (int j = 0; j < 8; ++j) {
                float x = xv[j];
                u16 h = bfhi(x);
                hv[j] = h;
                lv[j] = bfhi(x - bf2f(h));
            }
            *(uint4*)(&BH[wrB]) = *(uint4*)hv;
            *(uint4*)(&BL[wrB]) = *(uint4*)lv;
        }
        // 3) counted wait: A(kq) landed, A(kq+1) still in flight; ds_writes done
        if (kq < 7)
            asm volatile("s_waitcnt vmcnt(4) lgkmcnt(0)" ::: "memory");
        else
            asm volatile("s_waitcnt vmcnt(0) lgkmcnt(0)" ::: "memory");
        __builtin_amdgcn_s_barrier();
        __builtin_amdgcn_sched_barrier(0);
        // 4) issue next-tile B f32 loads (hide under MFMA)
        if (kq < 7) {
#pragma unroll
            for (int j = 0; j < 8; ++j)
                xv[j] = bp[(size_t)((kq + 1) * 32 + j) * NPOS];
        }
        // 5) MFMA
        short8 bh[4], bl[4];
#pragma unroll
        for (int r = 0; r < 4; ++r) {
            bh[r] = *(const short8*)(&BH[offB0 + r * 512]);
            bl[r] = *(const short8*)(&BL[offB0 + r * 512]);
        }
#pragma unroll
        for (int f = 0; f < 4; ++f) {
            short8 ah = *(const short8*)(&Acur[offA0 + f * 512]);
            short8 al = *(const short8*)(&Acur[8192 + offA0 + f * 512]);
#pragma unroll
            for (int r = 0; r < 4; ++r) {
                acc[f][r] = __builtin_amdgcn_mfma_f32_16x16x32_bf16(ah, bh[r], acc[f][r], 0, 0, 0);
                acc[f][r] = __builtin_amdgcn_mfma_f32_16x16x32_bf16(ah, bl[r], acc[f][r], 0, 0, 0);
                acc[f][r] = __builtin_amdgcn_mfma_f32_16x16x32_bf16(al, bh[r], acc[f][r], 0, 0, 0);
            }
        }
        // 6) raw execution barrier (no drain): protects B + bufA[nxt] overwrite
        __builtin_amdgcn_s_barrier();
    }

    // ---- vectorized epilogue: per-wave LDS bounce (aliased onto bufA) ----
    float* SB = (float*)LDSBUF + (size_t)wv * (16 * 68);
    const float* wmap = ((mat == 0) ? wvis : wir) + (size_t)b * NPOS;
    const float* bias = (mat == 0) ? qb : (mat == 1) ? kbias : vb;
    float* outp = ((mat == 0) ? qo : (mat == 1) ? ko : vo) + (size_t)b * PERB;
    bool addpe = (mat != 2);

    int lane = t & 63;
    int lrow = lane >> 2;
    int lq   = lane & 3;
    int base_n = bn * 128 + wn * 64;

#pragma unroll
    for (int f = 0; f < 4; ++f) {
#pragma unroll
        for (int r = 0; r < 4; ++r)
#pragma unroll
            for (int ri = 0; ri < 4; ++ri)
                SB[(gq * 4 + ri) * 68 + (r * 16 + rr)] = acc[f][r][ri];
        int o = wm * 64 + f * 16 + lrow;
        float bo = bias[o];
        const float* tro = Ttab + o * 96;
        float* orow = outp + (size_t)o * NPOS;
#pragma unroll
        for (int qd = 0; qd < 4; ++qd) {
            int c0 = lq * 16 + qd * 4;
            int n = base_n + c0;
            float4 v4 = *(float4*)&SB[lrow * 68 + c0];
            float4 s4 = *(const float4*)&wmap[n];
            float4 o4;
            if (addpe) {
                int hh = n / 96, ww = n - hh * 96;
                float4 pw4 = *(const float4*)&tro[ww];
                float ph = tro[hh];
                o4.x = v4.x * s4.x + bo + pw4.x + ph;
                o4.y = v4.y * s4.y + bo + pw4.y + ph;
                o4.z = v4.z * s4.z + bo + pw4.z + ph;
                o4.w = v4.w * s4.w + bo + pw4.w + ph;
            } else {
                o4.x = v4.x * s4.x + bo;
                o4.y = v4.y * s4.y + bo;
                o4.z = v4.z * s4.z + bo;
                o4.w = v4.w * s4.w + bo;
            }
            *(float4*)&orow[n] = o4;
        }
    }
}

// ---------------------------------------------------------------------------
// MFMA attention per (b,c) plane (round-16, unchanged): 192 threads = 3 waves.
// ---------------------------------------------------------------------------
__global__ __launch_bounds__(192, 2) void attn_mfma(
    const float* __restrict__ q, const float* __restrict__ k,
    const float* __restrict__ v, float* __restrict__ fused)
{
    __shared__ char LB[76800];
    u16* QH = (u16*)LB;                 // later PH
    u16* QL = (u16*)(LB + 19200);       // later PL
    u16* KH = (u16*)(LB + 38400);       // later VTH
    u16* KL = (u16*)(LB + 57600);       // later VTL
    float* OB = (float*)LB;             // [96][100] bounce (aliases QH/QL)

    int t = threadIdx.x;
    int bc = blockIdx.x;
    size_t base = (size_t)bc * NPOS;
    int wq = t >> 6, rr = t & 15, gq = (t >> 4) & 3;
    int sxor = (gq ^ ((rr >> 1) & 3)) * 8;

    // ---- stage Q,K ----
#pragma unroll
    for (int i = 0; i < 12; ++i) {
        int idx = i * 192 + t;
        int row = idx / 24, c4 = (idx % 24) * 4;
        int tile = c4 >> 5, kin = c4 & 31;
        int a = tile * 3072 + row * 32 + (((kin >> 3) ^ ((row >> 1) & 3)) << 3) + (kin & 7);
        float4 qv = *(const float4*)(q + base + row * 96 + c4);
        float4 kv = *(const float4*)(k + base + row * 96 + c4);
        unsigned int qh01, qh23, ql01, ql23, kh01, kh23, kl01, kl23;
        {
            u16 h0 = bfhi(qv.x), h1 = bfhi(qv.y), h2 = bfhi(qv.z), h3 = bfhi(qv.w);
            u16 l0 = bfhi(qv.x - bf2f(h0)), l1 = bfhi(qv.y - bf2f(h1));
            u16 l2 = bfhi(qv.z - bf2f(h2)), l3 = bfhi(qv.w - bf2f(h3));
            qh01 = (unsigned)h0 | ((unsigned)h1 << 16); qh23 = (unsigned)h2 | ((unsigned)h3 << 16);
            ql01 = (unsigned)l0 | ((unsigned)l1 << 16); ql23 = (unsigned)l2 | ((unsigned)l3 << 16);
        }
        {
            u16 h0 = bfhi(kv.x), h1 = bfhi(kv.y), h2 = bfhi(kv.z), h3 = bfhi(kv.w);
            u16 l0 = bfhi(kv.x - bf2f(h0)), l1 = bfhi(kv.y - bf2f(h1));
            u16 l2 = bfhi(kv.z - bf2f(h2)), l3 = bfhi(kv.w - bf2f(h3));
            kh01 = (unsigned)h0 | ((unsigned)h1 << 16); kh23 = (unsigned)h2 | ((unsigned)h3 << 16);
            kl01 = (unsigned)l0 | ((unsigned)l1 << 16); kl23 = (unsigned)l2 | ((unsigned)l3 << 16);
        }
        *(uint2*)(QH + a) = (uint2){qh01, qh23};
        *(uint2*)(QL + a) = (uint2){ql01, ql23};
        *(uint2*)(KH + a) = (uint2){kh01, kh23};
        *(uint2*)(KL + a) = (uint2){kl01, kl23};
    }
    __syncthreads();

    // ---- QK^T (4-term split) ----
    f32x4 acc[2][6];
#pragma unroll
    for (int mt = 0; mt < 2; ++mt)
#pragma unroll
        for (int nt = 0; nt < 6; ++nt) acc[mt][nt] = (f32x4){0.f, 0.f, 0.f, 0.f};

#pragma unroll
    for (int ks = 0; ks < 3; ++ks) {
        short8 qh2[2], ql2[2], kh6[6], kl6[6];
#pragma unroll
        for (int mt = 0; mt < 2; ++mt) {
            int ra = ks * 3072 + (wq * 32 + mt * 16 + rr) * 32 + sxor;
            qh2[mt] = *(const short8*)(QH + ra);
            ql2[mt] = *(const short8*)(QL + ra);
        }
#pragma unroll
        for (int nt = 0; nt < 6; ++nt) {
            int rb = ks * 3072 + (nt * 16 + rr) * 32 + sxor;
            kh6[nt] = *(const short8*)(KH + rb);
            kl6[nt] = *(const short8*)(KL + rb);
        }
#pragma unroll
        for (int mt = 0; mt < 2; ++mt)
#pragma unroll
            for (int nt = 0; nt < 6; ++nt) {
                acc[mt][nt] = __builtin_amdgcn_mfma_f32_16x16x32_bf16(qh2[mt], kh6[nt], acc[mt][nt], 0, 0, 0);
                acc[mt][nt] = __builtin_amdgcn_mfma_f32_16x16x32_bf16(qh2[mt], kl6[nt], acc[mt][nt], 0, 0, 0);
                acc[mt][nt] = __builtin_amdgcn_mfma_f32_16x16x32_bf16(ql2[mt], kh6[nt], acc[mt][nt], 0, 0, 0);
                acc[mt][nt] = __builtin_amdgcn_mfma_f32_16x16x32_bf16(ql2[mt], kl6[nt], acc[mt][nt], 0, 0, 0);
            }
    }

    // ---- softmax over g ----
#pragma unroll
    for (int mt = 0; mt < 2; ++mt)
#pragma unroll
        for (int ri = 0; ri < 4; ++ri) {
            float mx = acc[mt][0][ri];
#pragma unroll
            for (int nt = 1; nt < 6; ++nt) mx = fmaxf(mx, acc[mt][nt][ri]);
            for (int dd = 1; dd < 16; dd <<= 1) mx = fmaxf(mx, __shfl_xor(mx, dd));
            float s = 0.0f;
#pragma unroll
            for (int nt = 0; nt < 6; ++nt) {
                float e = __expf(acc[mt][nt][ri] - mx);
                acc[mt][nt][ri] = e;
                s += e;
            }
            for (int dd = 1; dd < 16; dd <<= 1) s += __shfl_xor(s, dd);
            float inv = 1.0f / s;
#pragma unroll
            for (int nt = 0; nt < 6; ++nt) acc[mt][nt][ri] *= inv;
        }

    __syncthreads();

    // ---- write P (into Q regions) + stage V^T (into K regions) ----
#pragma unroll
    for (int mt = 0; mt < 2; ++mt)
#pragma unroll
        for (int ri = 0; ri < 4; ++ri) {
            int row = wq * 32 + mt * 16 + gq * 4 + ri;
            int keyr = (row >> 1) & 3;
#pragma unroll
            for (int nt = 0; nt < 6; ++nt) {
                float val = acc[mt][nt][ri];
                u16 h = bfhi(val);
                u16 l = bfhi(val - bf2f(h));
                int slot = ((nt & 1) << 1) | (rr >> 3);
                int a = (nt >> 1) * 3072 + row * 32 + ((slot ^ keyr) << 3) + (rr & 7);
                QH[a] = h;
                QL[a] = l;
            }
        }
#pragma unroll
    for (int i = 0; i < 12; ++i) {
        int idx = i * 192 + t;
        int grow = idx / 24, c4 = (idx % 24) * 4;
        float4 vv = *(const float4*)(v + base + grow * 96 + c4);
        int tile = grow >> 5, kin = grow & 31;
        int slot = kin >> 3, off = kin & 7;
#pragma unroll
        for (int e = 0; e < 4; ++e) {
            int w = c4 + e;
            float val = (e == 0) ? vv.x : (e == 1) ? vv.y : (e == 2) ? vv.z : vv.w;
            u16 h = bfhi(val);
            u16 l = bfhi(val - bf2f(h));
            int a = tile * 3072 + w * 32 + ((slot ^ ((w >> 1) & 3)) << 3) + off;
            KH[a] = h;
            KL[a] = l;
        }
    }
    __syncthreads();

    // ---- PV (3-term split) ----
#pragma unroll
    for (int mt = 0; mt < 2; ++mt)
#pragma unroll
        for (int nt = 0; nt < 6; ++nt) acc[mt][nt] = (f32x4){0.f, 0.f, 0.f, 0.f};

#pragma unroll
    for (int ks = 0; ks < 3; ++ks) {
        short8 ph2[2], pl2[2], vh6[6], vl6[6];
#pragma unroll
        for (int mt = 0; mt < 2; ++mt) {
            int ra = ks * 3072 + (wq * 32 + mt * 16 + rr) * 32 + sxor;
            ph2[mt] = *(const short8*)(QH + ra);
            pl2[mt] = *(const short8*)(QL + ra);
        }
#pragma unroll
        for (int nt = 0; nt < 6; ++nt) {
            int rb = ks * 3072 + (nt * 16 + rr) * 32 + sxor;
            vh6[nt] = *(const short8*)(KH + rb);
            vl6[nt] = *(const short8*)(KL + rb);
        }
#pragma unroll
        for (int mt = 0; mt < 2; ++mt)
#pragma unroll
            for (int nt = 0; nt < 6; ++nt) {
                acc[mt][nt] = __builtin_amdgcn_mfma_f32_16x16x32_bf16(ph2[mt], vh6[nt], acc[mt][nt], 0, 0, 0);
                acc[mt][nt] = __builtin_amdgcn_mfma_f32_16x16x32_bf16(ph2[mt], vl6[nt], acc[mt][nt], 0, 0, 0);
                acc[mt][nt] = __builtin_amdgcn_mfma_f32_16x16x32_bf16(pl2[mt], vh6[nt], acc[mt][nt], 0, 0, 0);
            }
    }
    __syncthreads();

    // ---- f32 bounce + coalesced output ----
#pragma unroll
    for (int mt = 0; mt < 2; ++mt)
#pragma unroll
        for (int nt = 0; nt < 6; ++nt)
#pragma unroll
            for (int ri = 0; ri < 4; ++ri) {
                int row = wq * 32 + mt * 16 + gq * 4 + ri;
                OB[row * 100 + nt * 16 + rr] = acc[mt][nt][ri];
            }
    __syncthreads();
#pragma unroll
    for (int i = 0; i < 12; ++i) {
        int idx = i * 192 + t;
        int row = idx / 24, c4 = (idx % 24) * 4;
        float4 o = *(const float4*)&OB[row * 100 + c4];
        *(float4*)(fused + base + row * 96 + c4) = o;
    }
}

// ---------------------------------------------------------------------------
// Final projection: out[b][o][n] = sum_c proj_w[o][c]*fused[b][c][n] + pb[o]
// ---------------------------------------------------------------------------
__global__ __launch_bounds__(256) void proj_kernel(
    const float* __restrict__ fused, const float* __restrict__ pw,
    const float* __restrict__ pb, float* __restrict__ out)
{
    __shared__ float As[16 * 68];
    __shared__ float Bs[16 * 128];

    int t  = threadIdx.x;
    int n0 = blockIdx.x * 128;
    int b  = blockIdx.y;
    const float* B = fused + (size_t)b * PERB;
    int tx = t & 15, ty = t >> 4;

    float acc[4][8];
#pragma unroll
    for (int i = 0; i < 4; ++i)
#pragma unroll
        for (int j = 0; j < 8; ++j) acc[i][j] = 0.0f;

    for (int k0 = 0; k0 < 256; k0 += 16) {
        {
            int m = t >> 2, c4 = (t & 3) * 4;
            float4 av = *(const float4*)(pw + (size_t)m * 256 + k0 + c4);
            As[(c4 + 0) * 68 + m] = av.x;
            As[(c4 + 1) * 68 + m] = av.y;
            As[(c4 + 2) * 68 + m] = av.z;
            As[(c4 + 3) * 68 + m] = av.w;
        }
#pragma unroll
        for (int l = 0; l < 2; ++l) {
            int f = t + l * 256;
            int c = f >> 5, n4 = (f & 31) * 4;
            *(float4*)(Bs + c * 128 + n4) =
                *(const float4*)(B + (size_t)(k0 + c) * NPOS + n0 + n4);
        }
        __syncthreads();
#pragma unroll
        for (int kk = 0; kk < 16; ++kk) {
            float a[4], bb[8];
            *(float4*)(&a[0])  = *(const float4*)(As + kk * 68 + ty * 4);
            *(float4*)(&bb[0]) = *(const float4*)(Bs + kk * 128 + tx * 8);
            *(float4*)(&bb[4]) = *(const float4*)(Bs + kk * 128 + tx * 8 + 4);
#pragma unroll
            for (int i = 0; i < 4; ++i)
#pragma unroll
                for (int j = 0; j < 8; ++j)
                    acc[i][j] = fmaf(a[i], bb[j], acc[i][j]);
        }
        __syncthreads();
    }

    int n = n0 + tx * 8;
#pragma unroll
    for (int i = 0; i < 4; ++i) {
        int o = ty * 4 + i;
        float bias = pb[o];
        float vals[8];
#pragma unroll
        for (int j = 0; j < 8; ++j) vals[j] = acc[i][j] + bias;
        float* op = out + ((size_t)b * 64 + o) * NPOS + n;
        *(float4*)(op)     = *(float4*)(&vals[0]);
        *(float4*)(op + 4) = *(float4*)(&vals[4]);
    }
}

// ---------------------------------------------------------------------------
extern "C" void kernel_launch(void* const* d_in, const int* in_sizes, int n_in,
                              void* d_out, int out_size, void* d_ws, size_t ws_size,
                              hipStream_t stream)
{
    const float* x1   = (const float*)d_in[0];
    const float* x2   = (const float*)d_in[1];
    const float* wvis = (const float*)d_in[2];
    const float* wir  = (const float*)d_in[3];
    const float* qw   = (const float*)d_in[4];
    const float* qb   = (const float*)d_in[5];
    const float* kw   = (const float*)d_in[6];
    const float* kb   = (const float*)d_in[7];
    const float* vw   = (const float*)d_in[8];
    const float* vb   = (const float*)d_in[9];
    const float* pw   = (const float*)d_in[10];
    const float* pb   = (const float*)d_in[11];
    float* out = (float*)d_out;

    float* ws = (float*)d_ws;
    size_t F = ws_size / 4;
    size_t fixed = 350000;
    size_t avail = (F > fixed) ? (F - fixed) : 0;
    int G = (int)(avail / (4 * PERB));
    if (G < 1) G = 1;
    if (G > 8) G = 8;

    float* ttab  = ws;
    float* qbuf  = ws + 24576;
    float* kbuf  = qbuf + (size_t)G * PERB;
    float* vbuf  = kbuf + (size_t)G * PERB;
    float* fbuf  = vbuf + (size_t)G * PERB;
    u16*   whiP  = (u16*)(fbuf + (size_t)G * PERB);
    u16*   wloP  = whiP + 589824;

    tt_kernel<<<dim3(96), 256, 0, stream>>>(ttab);
    wsplit<<<dim3(144), 256, 0, stream>>>(qw, kw, vw, whiP, wloP);

    for (int b0 = 0; b0 < 16; b0 += G) {
        int g = (16 - b0 < G) ? (16 - b0) : G;
        for (int s = 0; s < 3; ++s) {
            const float* sq  = (s == 0) ? (x1 + (size_t)b0 * PERB) : fbuf;
            const float* skv = (s == 0) ? (x2 + (size_t)b0 * PERB) : fbuf;
            gemm_qkv_mfma<<<dim3(3, 72, g), 512, 0, stream>>>(
                whiP + (size_t)s * 196608, wloP + (size_t)s * 196608,
                sq, skv,
                qb + (size_t)s * 256, kb + (size_t)s * 256, vb + (size_t)s * 256,
                wvis + (size_t)b0 * NPOS, wir + (size_t)b0 * NPOS,
                ttab, qbuf, kbuf, vbuf);
            attn_mfma<<<dim3(256 * g), 192, 0, stream>>>(qbuf, kbuf, vbuf, fbuf);
        }
        proj_kernel<<<dim3(72, g), 256, 0, stream>>>(
            fbuf, pw, pb, out + (size_t)b0 * 64 * NPOS);
    }
}

// Round 18
// 1522.313 us; speedup vs baseline: 1.3662x; 1.3662x over previous
//
#include <hip/hip_runtime.h>
#include <hip/hip_bf16.h>
#include <math.h>

// Shapes: B=16, C=256, H=W=96, S=3, OUT_C=64
#define NPOS 9216
#define PERB 2359296ull        // 256*9216 elements (one [C][H*W] plane-set)

typedef unsigned short u16;
typedef __attribute__((ext_vector_type(8))) short short8;  // bf16x8 MFMA frag
typedef __attribute__((ext_vector_type(4))) float f32x4;   // MFMA acc

__device__ inline u16 bfhi(float x) {
    unsigned int b = __float_as_uint(x);
    return (u16)((b + 0x7FFFu + ((b >> 16) & 1u)) >> 16);   // RNE f32->bf16
}
__device__ inline float bf2f(u16 u) { return __uint_as_float(((unsigned int)u) << 16); }

// async global->LDS, 16B per lane (dest = uniform base + lane*16)
typedef const __attribute__((address_space(1))) void* gvp;
typedef __attribute__((address_space(3))) void* lvp;
__device__ __forceinline__ void glds16(const void* g, void* l) {
    __builtin_amdgcn_global_load_lds((gvp)g, (lvp)l, 16, 0, 0);
}

// ---------------------------------------------------------------------------
// Separable positional-encoding table: T[c][p], c=4j+r.
// ---------------------------------------------------------------------------
__global__ __launch_bounds__(256) void tt_kernel(float* __restrict__ T)
{
    int idx = blockIdx.x * 256 + threadIdx.x;   // 0..24575 (256c x 96p)
    int c = idx / 96, p = idx - (idx / 96) * 96;
    int j = c >> 2, r = c & 3;
    float f = expf(-(float)(2 * j) * 0.07195578415f);  // ln(10000)/128
    float x = (float)p * (1.0f / 95.0f) * f;
    T[idx] = (r == 0) ? sinf(x) : (r == 1) ? cosf(x) : 0.0f;
}

// ---------------------------------------------------------------------------
// Weight split: W[s][mat][256][256] f32 -> blocked bf16 hi/lo, XOR-swizzled.
// layout: [s][mat*2+mb][kb][128 rows][4 slots][8] with slot ^= (row>>1)&3
// ---------------------------------------------------------------------------
__global__ __launch_bounds__(256) void wsplit(
    const float* __restrict__ qw, const float* __restrict__ kw,
    const float* __restrict__ vw, u16* __restrict__ whi, u16* __restrict__ wlo)
{
    int bid = blockIdx.x;
    int s = bid / 48, rem = bid % 48;
    int mat = rem / 16, rem2 = rem % 16;
    int mb = rem2 / 8, kb = rem2 % 8;
    const float* W = ((mat == 0) ? qw : (mat == 1) ? kw : vw) + (size_t)s * 65536;
    int t = threadIdx.x;
    int m = t >> 1, kh = (t & 1) * 16;
    const float* src = W + (size_t)(mb * 128 + m) * 256 + kb * 32 + kh;
    int s0 = kh >> 3;                  // 0 or 2
    int sw = (m >> 1) & 3;
    size_t ob = (size_t)s * 196608 + (size_t)((mat * 2 + mb) * 8 + kb) * 4096
              + (size_t)m * 32;
    u16 hv[16], lv[16];
#pragma unroll
    for (int j = 0; j < 16; ++j) {
        float x = src[j];
        u16 h = bfhi(x);
        hv[j] = h;
        lv[j] = bfhi(x - bf2f(h));
    }
    *(uint4*)(whi + ob + ((s0 ^ sw) * 8))       = *(uint4*)hv;
    *(uint4*)(whi + ob + (((s0 + 1) ^ sw) * 8)) = *(uint4*)(hv + 8);
    *(uint4*)(wlo + ob + ((s0 ^ sw) * 8))       = *(uint4*)lv;
    *(uint4*)(wlo + ob + (((s0 + 1) ^ sw) * 8)) = *(uint4*)(lv + 8);
}

// ---------------------------------------------------------------------------
// MFMA QKV GEMM (round-16 fat-M structure: single-buffered A via glds16,
// B converted f32->hi/lo in LDS, counted RAW barrier after MFMA).
// ---------------------------------------------------------------------------
__global__ __launch_bounds__(512, 4) void gemm_qkv_mfma(
    const u16* __restrict__ whi, const u16* __restrict__ wlo,
    const float* __restrict__ srcq, const float* __restrict__ srckv,
    const float* __restrict__ qb, const float* __restrict__ kbias,
    const float* __restrict__ vb, const float* __restrict__ wvis,
    const float* __restrict__ wir, const float* __restrict__ Ttab,
    float* __restrict__ qo, float* __restrict__ ko, float* __restrict__ vo)
{
    __shared__ char LDSBUF[49152];
    u16* AH = (u16*)LDSBUF;
    u16* AL = AH + 8192;
    u16* BH = AL + 8192;
    u16* BL = BH + 4096;

    int t = threadIdx.x;
    int d = blockIdx.x + 3 * blockIdx.y;           // 0..215
    int role = (d & 7) * 27 + (d >> 3);
    int mat = role / 72, bn = role % 72;
    int b = blockIdx.z;

    const float* gB = ((mat == 0) ? srcq : srckv) + (size_t)b * PERB + bn * 128;
    const u16* gA0 = whi + (size_t)(mat * 2) * 32768;
    const u16* gA1 = wlo + (size_t)(mat * 2) * 32768;

    int wv = t >> 6;
    int wm = wv >> 1, wn = wv & 1;
    int rr = t & 15, gq = (t >> 4) & 3;

    int sxor = (gq ^ ((rr >> 1) & 3)) * 8;
    int offA0 = (wm * 64 + rr) * 32 + sxor;
    int offB0 = (wn * 64 + rr) * 32 + sxor;

    int arow = t >> 2, acol = (t & 3) * 8;
    size_t asrc0 = (size_t)arow * 32 + acol;
    size_t asrc1 = 32768 + (size_t)arow * 32 + acol;

    int bn_ = t & 127, bkh = t >> 7;
    int key = (bn_ >> 1) & 3;
    int wrB = bn_ * 32 + ((bkh ^ key) * 8);
    const float* bp = gB + (size_t)(bkh * 8) * NPOS + bn_;

    f32x4 acc[4][4];
#pragma unroll
    for (int i = 0; i < 4; ++i)
#pragma unroll
        for (int j = 0; j < 4; ++j) acc[i][j] = (f32x4){0.f, 0.f, 0.f, 0.f};

    float xv[8];
#pragma unroll
    for (int j = 0; j < 8; ++j) xv[j] = bp[(size_t)j * NPOS];

    for (int kq = 0; kq < 8; ++kq) {
        {
            glds16(gA0 + kq * 4096 + asrc0, &AH[t * 8]);
            glds16(gA0 + kq * 4096 + asrc1, &AH[t * 8 + 4096]);
            glds16(gA1 + kq * 4096 + asrc0, &AL[t * 8]);
            glds16(gA1 + kq * 4096 + asrc1, &AL[t * 8 + 4096]);
        }
        {
            u16 hv[8], lv[8];
#pragma unroll
            for (int j = 0; j < 8; ++j) {
                float x = xv[j];
                u16 h = bfhi(x);
                hv[j] = h;
                lv[j] = bfhi(x - bf2f(h));
            }
            *(uint4*)(&BH[wrB]) = *(uint4*)hv;
            *(uint4*)(&BL[wrB]) = *(uint4*)lv;
        }
        __syncthreads();

        if (kq < 7) {
#pragma unroll
            for (int j = 0; j < 8; ++j)
                xv[j] = bp[(size_t)((kq + 1) * 32 + j) * NPOS];
        }

        short8 bh[4], bl[4];
#pragma unroll
        for (int r = 0; r < 4; ++r) {
            bh[r] = *(const short8*)(&BH[offB0 + r * 512]);
            bl[r] = *(const short8*)(&BL[offB0 + r * 512]);
        }
#pragma unroll
        for (int f = 0; f < 4; ++f) {
            short8 ah = *(const short8*)(&AH[offA0 + f * 512]);
            short8 al = *(const short8*)(&AL[offA0 + f * 512]);
#pragma unroll
            for (int r = 0; r < 4; ++r) {
                acc[f][r] = __builtin_amdgcn_mfma_f32_16x16x32_bf16(ah, bh[r], acc[f][r], 0, 0, 0);
                acc[f][r] = __builtin_amdgcn_mfma_f32_16x16x32_bf16(ah, bl[r], acc[f][r], 0, 0, 0);
                acc[f][r] = __builtin_amdgcn_mfma_f32_16x16x32_bf16(al, bh[r], acc[f][r], 0, 0, 0);
            }
        }
        asm volatile("s_waitcnt lgkmcnt(0)" ::: "memory");
        __builtin_amdgcn_s_barrier();
        __builtin_amdgcn_sched_barrier(0);
    }

    float* SB = (float*)LDSBUF + (size_t)wv * (16 * 68);
    const float* wmap = ((mat == 0) ? wvis : wir) + (size_t)b * NPOS;
    const float* bias = (mat == 0) ? qb : (mat == 1) ? kbias : vb;
    float* outp = ((mat == 0) ? qo : (mat == 1) ? ko : vo) + (size_t)b * PERB;
    bool addpe = (mat != 2);

    int lane = t & 63;
    int lrow = lane >> 2;
    int lq   = lane & 3;
    int base_n = bn * 128 + wn * 64;

#pragma unroll
    for (int f = 0; f < 4; ++f) {
#pragma unroll
        for (int r = 0; r < 4; ++r)
#pragma unroll
            for (int ri = 0; ri < 4; ++ri)
                SB[(gq * 4 + ri) * 68 + (r * 16 + rr)] = acc[f][r][ri];
        int o = wm * 64 + f * 16 + lrow;
        float bo = bias[o];
        const float* tro = Ttab + o * 96;
        float* orow = outp + (size_t)o * NPOS;
#pragma unroll
        for (int qd = 0; qd < 4; ++qd) {
            int c0 = lq * 16 + qd * 4;
            int n = base_n + c0;
            float4 v4 = *(float4*)&SB[lrow * 68 + c0];
            float4 s4 = *(const float4*)&wmap[n];
            float4 o4;
            if (addpe) {
                int hh = n / 96, ww = n - hh * 96;
                float4 pw4 = *(const float4*)&tro[ww];
                float ph = tro[hh];
                o4.x = v4.x * s4.x + bo + pw4.x + ph;
                o4.y = v4.y * s4.y + bo + pw4.y + ph;
                o4.z = v4.z * s4.z + bo + pw4.z + ph;
                o4.w = v4.w * s4.w + bo + pw4.w + ph;
            } else {
                o4.x = v4.x * s4.x + bo;
                o4.y = v4.y * s4.y + bo;
                o4.z = v4.z * s4.z + bo;
                o4.w = v4.w * s4.w + bo;
            }
            *(float4*)&orow[n] = o4;
        }
    }
}

// ---------------------------------------------------------------------------
// MFMA attention per (b,c) plane: 192 threads = 3 waves, wave owns 32 rows.
// V^T staging now uses per-thread 4x4 transpose blocks -> ds_write_b64.
// ---------------------------------------------------------------------------
__global__ __launch_bounds__(192, 2) void attn_mfma(
    const float* __restrict__ q, const float* __restrict__ k,
    const float* __restrict__ v, float* __restrict__ fused)
{
    __shared__ char LB[76800];
    u16* QH = (u16*)LB;                 // later PH
    u16* QL = (u16*)(LB + 19200);       // later PL
    u16* KH = (u16*)(LB + 38400);       // later VTH
    u16* KL = (u16*)(LB + 57600);       // later VTL
    float* OB = (float*)LB;             // [96][100] bounce (aliases QH/QL)

    int t = threadIdx.x;
    int bc = blockIdx.x;
    size_t base = (size_t)bc * NPOS;
    int wq = t >> 6, rr = t & 15, gq = (t >> 4) & 3;
    int sxor = (gq ^ ((rr >> 1) & 3)) * 8;

    // ---- stage Q,K ----
#pragma unroll
    for (int i = 0; i < 12; ++i) {
        int idx = i * 192 + t;
        int row = idx / 24, c4 = (idx % 24) * 4;
        int tile = c4 >> 5, kin = c4 & 31;
        int a = tile * 3072 + row * 32 + (((kin >> 3) ^ ((row >> 1) & 3)) << 3) + (kin & 7);
        float4 qv = *(const float4*)(q + base + row * 96 + c4);
        float4 kv = *(const float4*)(k + base + row * 96 + c4);
        unsigned int qh01, qh23, ql01, ql23, kh01, kh23, kl01, kl23;
        {
            u16 h0 = bfhi(qv.x), h1 = bfhi(qv.y), h2 = bfhi(qv.z), h3 = bfhi(qv.w);
            u16 l0 = bfhi(qv.x - bf2f(h0)), l1 = bfhi(qv.y - bf2f(h1));
            u16 l2 = bfhi(qv.z - bf2f(h2)), l3 = bfhi(qv.w - bf2f(h3));
            qh01 = (unsigned)h0 | ((unsigned)h1 << 16); qh23 = (unsigned)h2 | ((unsigned)h3 << 16);
            ql01 = (unsigned)l0 | ((unsigned)l1 << 16); ql23 = (unsigned)l2 | ((unsigned)l3 << 16);
        }
        {
            u16 h0 = bfhi(kv.x), h1 = bfhi(kv.y), h2 = bfhi(kv.z), h3 = bfhi(kv.w);
            u16 l0 = bfhi(kv.x - bf2f(h0)), l1 = bfhi(kv.y - bf2f(h1));
            u16 l2 = bfhi(kv.z - bf2f(h2)), l3 = bfhi(kv.w - bf2f(h3));
            kh01 = (unsigned)h0 | ((unsigned)h1 << 16); kh23 = (unsigned)h2 | ((unsigned)h3 << 16);
            kl01 = (unsigned)l0 | ((unsigned)l1 << 16); kl23 = (unsigned)l2 | ((unsigned)l3 << 16);
        }
        *(uint2*)(QH + a) = (uint2){qh01, qh23};
        *(uint2*)(QL + a) = (uint2){ql01, ql23};
        *(uint2*)(KH + a) = (uint2){kh01, kh23};
        *(uint2*)(KL + a) = (uint2){kl01, kl23};
    }
    __syncthreads();

    // ---- QK^T (4-term split) ----
    f32x4 acc[2][6];
#pragma unroll
    for (int mt = 0; mt < 2; ++mt)
#pragma unroll
        for (int nt = 0; nt < 6; ++nt) acc[mt][nt] = (f32x4){0.f, 0.f, 0.f, 0.f};

#pragma unroll
    for (int ks = 0; ks < 3; ++ks) {
        short8 qh2[2], ql2[2], kh6[6], kl6[6];
#pragma unroll
        for (int mt = 0; mt < 2; ++mt) {
            int ra = ks * 3072 + (wq * 32 + mt * 16 + rr) * 32 + sxor;
            qh2[mt] = *(const short8*)(QH + ra);
            ql2[mt] = *(const short8*)(QL + ra);
        }
#pragma unroll
        for (int nt = 0; nt < 6; ++nt) {
            int rb = ks * 3072 + (nt * 16 + rr) * 32 + sxor;
            kh6[nt] = *(const short8*)(KH + rb);
            kl6[nt] = *(const short8*)(KL + rb);
        }
#pragma unroll
        for (int mt = 0; mt < 2; ++mt)
#pragma unroll
            for (int nt = 0; nt < 6; ++nt) {
                acc[mt][nt] = __builtin_amdgcn_mfma_f32_16x16x32_bf16(qh2[mt], kh6[nt], acc[mt][nt], 0, 0, 0);
                acc[mt][nt] = __builtin_amdgcn_mfma_f32_16x16x32_bf16(qh2[mt], kl6[nt], acc[mt][nt], 0, 0, 0);
                acc[mt][nt] = __builtin_amdgcn_mfma_f32_16x16x32_bf16(ql2[mt], kh6[nt], acc[mt][nt], 0, 0, 0);
                acc[mt][nt] = __builtin_amdgcn_mfma_f32_16x16x32_bf16(ql2[mt], kl6[nt], acc[mt][nt], 0, 0, 0);
            }
    }

    // ---- softmax over g ----
#pragma unroll
    for (int mt = 0; mt < 2; ++mt)
#pragma unroll
        for (int ri = 0; ri < 4; ++ri) {
            float mx = acc[mt][0][ri];
#pragma unroll
            for (int nt = 1; nt < 6; ++nt) mx = fmaxf(mx, acc[mt][nt][ri]);
            for (int dd = 1; dd < 16; dd <<= 1) mx = fmaxf(mx, __shfl_xor(mx, dd));
            float s = 0.0f;
#pragma unroll
            for (int nt = 0; nt < 6; ++nt) {
                float e = __expf(acc[mt][nt][ri] - mx);
                acc[mt][nt][ri] = e;
                s += e;
            }
            for (int dd = 1; dd < 16; dd <<= 1) s += __shfl_xor(s, dd);
            float inv = 1.0f / s;
#pragma unroll
            for (int nt = 0; nt < 6; ++nt) acc[mt][nt][ri] *= inv;
        }

    __syncthreads();

    // ---- write P (into Q regions) + stage V^T (into K regions) ----
#pragma unroll
    for (int mt = 0; mt < 2; ++mt)
#pragma unroll
        for (int ri = 0; ri < 4; ++ri) {
            int row = wq * 32 + mt * 16 + gq * 4 + ri;
            int keyr = (row >> 1) & 3;
#pragma unroll
            for (int nt = 0; nt < 6; ++nt) {
                float val = acc[mt][nt][ri];
                u16 h = bfhi(val);
                u16 l = bfhi(val - bf2f(h));
                int slot = ((nt & 1) << 1) | (rr >> 3);
                int a = (nt >> 1) * 3072 + row * 32 + ((slot ^ keyr) << 3) + (rr & 7);
                QH[a] = h;
                QL[a] = l;
            }
        }
    // V^T staging: per-thread 4x4 transpose blocks, b64 stores
#pragma unroll
    for (int i = 0; i < 3; ++i) {
        int idx = i * 192 + t;              // 0..575
        int gq4 = idx / 24, wq4 = idx % 24;
        int g0 = gq4 * 4, w0 = wq4 * 4;
        float4 r0 = *(const float4*)(v + base + (size_t)(g0 + 0) * 96 + w0);
        float4 r1 = *(const float4*)(v + base + (size_t)(g0 + 1) * 96 + w0);
        float4 r2 = *(const float4*)(v + base + (size_t)(g0 + 2) * 96 + w0);
        float4 r3 = *(const float4*)(v + base + (size_t)(g0 + 3) * 96 + w0);
        int tile = g0 >> 5, kin = g0 & 31;
        int slot = kin >> 3, off = kin & 7;   // off in {0,4}
#pragma unroll
        for (int j = 0; j < 4; ++j) {
            int w = w0 + j;
            float c0 = (j == 0) ? r0.x : (j == 1) ? r0.y : (j == 2) ? r0.z : r0.w;
            float c1 = (j == 0) ? r1.x : (j == 1) ? r1.y : (j == 2) ? r1.z : r1.w;
            float c2 = (j == 0) ? r2.x : (j == 1) ? r2.y : (j == 2) ? r2.z : r2.w;
            float c3 = (j == 0) ? r3.x : (j == 1) ? r3.y : (j == 2) ? r3.z : r3.w;
            u16 h0 = bfhi(c0), h1 = bfhi(c1), h2 = bfhi(c2), h3 = bfhi(c3);
            u16 l0 = bfhi(c0 - bf2f(h0)), l1 = bfhi(c1 - bf2f(h1));
            u16 l2 = bfhi(c2 - bf2f(h2)), l3 = bfhi(c3 - bf2f(h3));
            int a = tile * 3072 + w * 32 + ((slot ^ ((w >> 1) & 3)) << 3) + off;
            *(uint2*)(KH + a) = (uint2){(unsigned)h0 | ((unsigned)h1 << 16),
                                        (unsigned)h2 | ((unsigned)h3 << 16)};
            *(uint2*)(KL + a) = (uint2){(unsigned)l0 | ((unsigned)l1 << 16),
                                        (unsigned)l2 | ((unsigned)l3 << 16)};
        }
    }
    __syncthreads();

    // ---- PV (3-term split) ----
#pragma unroll
    for (int mt = 0; mt < 2; ++mt)
#pragma unroll
        for (int nt = 0; nt < 6; ++nt) acc[mt][nt] = (f32x4){0.f, 0.f, 0.f, 0.f};

#pragma unroll
    for (int ks = 0; ks < 3; ++ks) {
        short8 ph2[2], pl2[2], vh6[6], vl6[6];
#pragma unroll
        for (int mt = 0; mt < 2; ++mt) {
            int ra = ks * 3072 + (wq * 32 + mt * 16 + rr) * 32 + sxor;
            ph2[mt] = *(const short8*)(QH + ra);
            pl2[mt] = *(const short8*)(QL + ra);
        }
#pragma unroll
        for (int nt = 0; nt < 6; ++nt) {
            int rb = ks * 3072 + (nt * 16 + rr) * 32 + sxor;
            vh6[nt] = *(const short8*)(KH + rb);
            vl6[nt] = *(const short8*)(KL + rb);
        }
#pragma unroll
        for (int mt = 0; mt < 2; ++mt)
#pragma unroll
            for (int nt = 0; nt < 6; ++nt) {
                acc[mt][nt] = __builtin_amdgcn_mfma_f32_16x16x32_bf16(ph2[mt], vh6[nt], acc[mt][nt], 0, 0, 0);
                acc[mt][nt] = __builtin_amdgcn_mfma_f32_16x16x32_bf16(ph2[mt], vl6[nt], acc[mt][nt], 0, 0, 0);
                acc[mt][nt] = __builtin_amdgcn_mfma_f32_16x16x32_bf16(pl2[mt], vh6[nt], acc[mt][nt], 0, 0, 0);
            }
    }
    __syncthreads();

    // ---- f32 bounce + coalesced output ----
#pragma unroll
    for (int mt = 0; mt < 2; ++mt)
#pragma unroll
        for (int nt = 0; nt < 6; ++nt)
#pragma unroll
            for (int ri = 0; ri < 4; ++ri) {
                int row = wq * 32 + mt * 16 + gq * 4 + ri;
                OB[row * 100 + nt * 16 + rr] = acc[mt][nt][ri];
            }
    __syncthreads();
#pragma unroll
    for (int i = 0; i < 12; ++i) {
        int idx = i * 192 + t;
        int row = idx / 24, c4 = (idx % 24) * 4;
        float4 o = *(const float4*)&OB[row * 100 + c4];
        *(float4*)(fused + base + row * 96 + c4) = o;
    }
}

// ---------------------------------------------------------------------------
// Final projection: out[b][o][n] = sum_c proj_w[o][c]*fused[b][c][n] + pb[o]
// ---------------------------------------------------------------------------
__global__ __launch_bounds__(256) void proj_kernel(
    const float* __restrict__ fused, const float* __restrict__ pw,
    const float* __restrict__ pb, float* __restrict__ out)
{
    __shared__ float As[16 * 68];
    __shared__ float Bs[16 * 128];

    int t  = threadIdx.x;
    int n0 = blockIdx.x * 128;
    int b  = blockIdx.y;
    const float* B = fused + (size_t)b * PERB;
    int tx = t & 15, ty = t >> 4;

    float acc[4][8];
#pragma unroll
    for (int i = 0; i < 4; ++i)
#pragma unroll
        for (int j = 0; j < 8; ++j) acc[i][j] = 0.0f;

    for (int k0 = 0; k0 < 256; k0 += 16) {
        {
            int m = t >> 2, c4 = (t & 3) * 4;
            float4 av = *(const float4*)(pw + (size_t)m * 256 + k0 + c4);
            As[(c4 + 0) * 68 + m] = av.x;
            As[(c4 + 1) * 68 + m] = av.y;
            As[(c4 + 2) * 68 + m] = av.z;
            As[(c4 + 3) * 68 + m] = av.w;
        }
#pragma unroll
        for (int l = 0; l < 2; ++l) {
            int f = t + l * 256;
            int c = f >> 5, n4 = (f & 31) * 4;
            *(float4*)(Bs + c * 128 + n4) =
                *(const float4*)(B + (size_t)(k0 + c) * NPOS + n0 + n4);
        }
        __syncthreads();
#pragma unroll
        for (int kk = 0; kk < 16; ++kk) {
            float a[4], bb[8];
            *(float4*)(&a[0])  = *(const float4*)(As + kk * 68 + ty * 4);
            *(float4*)(&bb[0]) = *(const float4*)(Bs + kk * 128 + tx * 8);
            *(float4*)(&bb[4]) = *(const float4*)(Bs + kk * 128 + tx * 8 + 4);
#pragma unroll
            for (int i = 0; i < 4; ++i)
#pragma unroll
                for (int j = 0; j < 8; ++j)
                    acc[i][j] = fmaf(a[i], bb[j], acc[i][j]);
        }
        __syncthreads();
    }

    int n = n0 + tx * 8;
#pragma unroll
    for (int i = 0; i < 4; ++i) {
        int o = ty * 4 + i;
        float bias = pb[o];
        float vals[8];
#pragma unroll
        for (int j = 0; j < 8; ++j) vals[j] = acc[i][j] + bias;
        float* op = out + ((size_t)b * 64 + o) * NPOS + n;
        *(float4*)(op)     = *(float4*)(&vals[0]);
        *(float4*)(op + 4) = *(float4*)(&vals[4]);
    }
}

// ---------------------------------------------------------------------------
extern "C" void kernel_launch(void* const* d_in, const int* in_sizes, int n_in,
                              void* d_out, int out_size, void* d_ws, size_t ws_size,
                              hipStream_t stream)
{
    const float* x1   = (const float*)d_in[0];
    const float* x2   = (const float*)d_in[1];
    const float* wvis = (const float*)d_in[2];
    const float* wir  = (const float*)d_in[3];
    const float* qw   = (const float*)d_in[4];
    const float* qb   = (const float*)d_in[5];
    const float* kw   = (const float*)d_in[6];
    const float* kb   = (const float*)d_in[7];
    const float* vw   = (const float*)d_in[8];
    const float* vb   = (const float*)d_in[9];
    const float* pw   = (const float*)d_in[10];
    const float* pb   = (const float*)d_in[11];
    float* out = (float*)d_out;

    float* ws = (float*)d_ws;
    size_t F = ws_size / 4;
    size_t fixed = 350000;
    size_t avail = (F > fixed) ? (F - fixed) : 0;
    int G = (int)(avail / (4 * PERB));
    if (G < 1) G = 1;
    if (G > 8) G = 8;

    float* ttab  = ws;
    float* qbuf  = ws + 24576;
    float* kbuf  = qbuf + (size_t)G * PERB;
    float* vbuf  = kbuf + (size_t)G * PERB;
    float* fbuf  = vbuf + (size_t)G * PERB;
    u16*   whiP  = (u16*)(fbuf + (size_t)G * PERB);
    u16*   wloP  = whiP + 589824;

    tt_kernel<<<dim3(96), 256, 0, stream>>>(ttab);
    wsplit<<<dim3(144), 256, 0, stream>>>(qw, kw, vw, whiP, wloP);

    for (int b0 = 0; b0 < 16; b0 += G) {
        int g = (16 - b0 < G) ? (16 - b0) : G;
        for (int s = 0; s < 3; ++s) {
            const float* sq  = (s == 0) ? (x1 + (size_t)b0 * PERB) : fbuf;
            const float* skv = (s == 0) ? (x2 + (size_t)b0 * PERB) : fbuf;
            gemm_qkv_mfma<<<dim3(3, 72, g), 512, 0, stream>>>(
                whiP + (size_t)s * 196608, wloP + (size_t)s * 196608,
                sq, skv,
                qb + (size_t)s * 256, kb + (size_t)s * 256, vb + (size_t)s * 256,
                wvis + (size_t)b0 * NPOS, wir + (size_t)b0 * NPOS,
                ttab, qbuf, kbuf, vbuf);
            attn_mfma<<<dim3(256 * g), 192, 0, stream>>>(qbuf, kbuf, vbuf, fbuf);
        }
        proj_kernel<<<dim3(72, g), 256, 0, stream>>>(
            fbuf, pw, pb, out + (size_t)b0 * 64 * NPOS);
    }
}